// Round 20
// baseline (124.752 us; speedup 1.0000x reference)
//
#include <hip/hip_runtime.h>
#include <hip/hip_fp16.h>
#include <math.h>

typedef _Float16 f16;
typedef _Float16 half8 __attribute__((ext_vector_type(8)));
typedef _Float16 half4v __attribute__((ext_vector_type(4)));
typedef _Float16 half2v __attribute__((ext_vector_type(2)));
typedef float f32x4 __attribute__((ext_vector_type(4)));

// ---------------- ws layout (bytes) ----------------
// sh1  @ 0MB   fp16 [1024][1024]
// sh2  @ 2MB   fp16 [1024][1024]
// w2t  @ 6MB   fp16 [1024][1024]
// wcat @ 8MB   fp16 [512][1024]
// bcat @ 9MB   fp32 [512]
// fmapT@ 9.5MB fp16 [21504][256]  (levels 3,4,5 at px 0,16384,20480) ends 20MB
// part @ 10MB  gemm1: f16 [8][1024][1024]=16MB; gemm2/3: fp32 (reused), ends 42MB
// pooled @ 44,564,480  fp16 [1024][49*256]
// w1t    @ 70,254,592  fp16 [1024][49*256]   (total 95,944,704 B)

__device__ __forceinline__ void gload16(const void* g, void* lds) {
  __builtin_amdgcn_global_load_lds(
      (const __attribute__((address_space(1))) unsigned int*)g,
      (__attribute__((address_space(3))) unsigned int*)lds, 16, 0, 0);
}

// ======== prep bodies (r16/r19-proven, unchanged) ========
__device__ __forceinline__ void fmap_body64(int b, f16* tile,
                                            const float* __restrict__ p3,
                                            const float* __restrict__ p4,
                                            const float* __restrict__ p5,
                                            f16* __restrict__ dst0) {
  const float* src;
  int Ppix, p0;
  size_t dstoff;
  if (b < 256)      { src = p3; Ppix = 16384; dstoff = 0;     p0 = b * 64; }
  else if (b < 320) { src = p4; Ppix = 4096;  dstoff = 16384; p0 = (b - 256) * 64; }
  else              { src = p5; Ppix = 1024;  dstoff = 20480; p0 = (b - 320) * 64; }
  const int t = threadIdx.x;
  const int px4 = (t & 15) * 4;   // 0..60
  const int cp = (t >> 4) * 2;    // 0..30
#pragma unroll
  for (int i = 0; i < 8; i++) {
    const int c = i * 32 + cp;
    const float4 va = *(const float4*)&src[(size_t)c * Ppix + p0 + px4];
    const float4 vb = *(const float4*)&src[(size_t)(c + 1) * Ppix + p0 + px4];
    const float a_[4] = {va.x, va.y, va.z, va.w};
    const float b_[4] = {vb.x, vb.y, vb.z, vb.w};
#pragma unroll
    for (int j = 0; j < 4; j++) {
      const int px = px4 + j;
      const int cs = c ^ (((px >> 2) & 31) << 3);  // flips bits>=3, parity kept
      half2v h = {(f16)a_[j], (f16)b_[j]};
      *(half2v*)&tile[px * 256 + cs] = h;
    }
  }
  __syncthreads();
  f16* d = dst0 + (dstoff + (size_t)p0) * 256;
  const int c8 = (t & 31) * 8;
  const int pxw = t >> 5;  // 0..7
#pragma unroll
  for (int i = 0; i < 8; i++) {
    const int px = i * 8 + pxw;
    const int c8s = c8 ^ (((px >> 2) & 31) << 3);
    const half8 o = *(const half8*)&tile[px * 256 + c8s];
    *(half8*)&d[px * 256 + c8] = o;
  }
}

// w1 repack v3 (r16-proven): phase-1 via global_load_lds.
// buf layout: raw fp32 [6272] at buf[0] (25,088B); tile f16 [49*260] at buf+12544.
__device__ __forceinline__ void w1t_body(int k, f16* buf,
                                         const float* __restrict__ w1,
                                         f16* __restrict__ w1t) {
  const int t = threadIdx.x;
  float* raw = (float*)buf;
  f16* tile = buf + 12544;
  const float* src = w1 + (size_t)k * 12544;
  f16* dst = w1t + (size_t)k * 12544;
#pragma unroll
  for (int h = 0; h < 2; h++) {
    const float* sh_ = src + h * 6272;   // c in [128h, 128h+128): 6272 floats
#pragma unroll
    for (int j = 0; j < 6; j++)
      gload16(sh_ + (size_t)(j * 256 + t) * 4, raw + (size_t)(j * 256 + t) * 4);
    float4 tail;
    if (t < 32) tail = *(const float4*)&sh_[(1536 + t) * 4];
    asm volatile("s_waitcnt vmcnt(0)" ::: "memory");
    __builtin_amdgcn_sched_barrier(0);
    if (t < 32) *(float4*)&raw[(1536 + t) * 4] = tail;
    __syncthreads();
#pragma unroll
    for (int i = 0; i < 25; i++) {
      const int v = i * 256 + t;
      if (v < 6272) {
        const int c = v / 49, pq = v - c * 49;
        tile[pq * 260 + (h * 128 + c)] = (f16)raw[v];
      }
    }
    __syncthreads();
  }
#pragma unroll
  for (int i = 0; i < 7; i++) {
    const int h8 = i * 256 + t;
    if (h8 < 1568) {
      const int pq = h8 >> 5, c8 = (h8 & 31) * 8;
      const half4v lo = *(const half4v*)&tile[pq * 260 + c8];
      const half4v hi = *(const half4v*)&tile[pq * 260 + c8 + 4];
      half8 o;
      o[0] = lo[0]; o[1] = lo[1]; o[2] = lo[2]; o[3] = lo[3];
      o[4] = hi[0]; o[5] = hi[1]; o[6] = hi[2]; o[7] = hi[3];
      *(half8*)&dst[pq * 256 + c8] = o;
    }
  }
}

// ---- launch A: streaming w1 repack ALONE (isolated from slow patterns) ----
__global__ __launch_bounds__(256) void w1t_only_k(const float* __restrict__ conv1_w,
                                                  f16* __restrict__ w1t) {
  __shared__ __align__(16) f16 buf[25600];  // 50 KB
  w1t_body(blockIdx.x, buf, conv1_w, w1t);
}

// ---- launch B: gather [0,1000) + fmap [1000,1336) + small [1336,2873) ----
__global__ __launch_bounds__(256) void rest_prep_k(
    const float* __restrict__ p2, const float* __restrict__ p3,
    const float* __restrict__ p4, const float* __restrict__ p5,
    const float* __restrict__ rois, const float* __restrict__ conv2_w,
    const float* __restrict__ lw, const float* __restrict__ lb,
    const float* __restrict__ bw, const float* __restrict__ bb,
    f16* __restrict__ fmapT, f16* __restrict__ pooled, f16* __restrict__ w2t,
    f16* __restrict__ wcat, float* __restrict__ bcat) {
  __shared__ __align__(16) f16 buf[16384];  // 32 KB union
  const int bid = blockIdx.x;
  const int t = threadIdx.x;
  if (bid < 1000) {
    // ---- level-2 gather (r11-proven v3): lane=position, wave=channel ----
    const int r = bid;
    const float x1 = rois[r * 4 + 0], y1 = rois[r * 4 + 1];
    const float x2 = rois[r * 4 + 2], y2 = rois[r * 4 + 3];
    const float s = sqrtf(fmaxf((y2 - y1) * (x2 - x1), 0.f));
    const float lf = logf(s / 224.0f) / 0.69314718055994531f;
    int lv = (int)rintf(lf) + 4;
    lv = lv < 2 ? 2 : (lv > 5 ? 5 : lv);
    if (lv != 2) return;
    const int wid = t >> 6, lane = t & 63;
    const float Hm1 = 255.f;
    int o00 = 0, o01 = 0, o10 = 0, o11 = 0;
    float wxl = 0.f, wyl = 0.f;
    bool vv = false;
    if (lane < 49) {
      const int py = lane / 7, px = lane % 7;
      const float y1n = y1 * (1.0f / 1024.0f), y2n = y2 * (1.0f / 1024.0f);
      const float x1n = x1 * (1.0f / 1024.0f), x2n = x2 * (1.0f / 1024.0f);
      const float cyc = y1n * Hm1 + ((float)py / 6.0f) * ((y2n - y1n) * Hm1);
      const float cxc = x1n * Hm1 + ((float)px / 6.0f) * ((x2n - x1n) * Hm1);
      const bool vy = (cyc >= 0.f) && (cyc <= Hm1);
      const bool vx = (cxc >= 0.f) && (cxc <= Hm1);
      float cy = fminf(fmaxf(cyc, 0.f), Hm1);
      float cx = fminf(fmaxf(cxc, 0.f), Hm1);
      const float fy = floorf(cy), fx = floorf(cx);
      const int ylo = (int)fy, xlo = (int)fx;
      const int yhi = (int)fminf(fy + 1.f, Hm1);
      const int xhi = (int)fminf(fx + 1.f, Hm1);
      wyl = cy - fy;
      wxl = cx - fx;
      vv = vy && vx;
      o00 = ylo * 256 + xlo;
      o01 = ylo * 256 + xhi;
      o10 = yhi * 256 + xlo;
      o11 = yhi * 256 + xhi;
    }
#pragma unroll 4
    for (int ci = 0; ci < 64; ci++) {
      const int ch = ci * 4 + wid;
      const float* pc = p2 + (size_t)ch * 65536;
      if (lane < 49) {
        const float v00 = pc[o00], v01 = pc[o01];
        const float v10 = pc[o10], v11 = pc[o11];
        const float top = v00 * (1.f - wxl) + v01 * wxl;
        const float bot = v10 * (1.f - wxl) + v11 * wxl;
        float val = top * (1.f - wyl) + bot * wyl;
        if (!vv) val = 0.f;
        buf[lane * 257 + ch] = (f16)val;
      }
    }
    __syncthreads();
    f16* outp = pooled + (size_t)r * 12544;
#pragma unroll 7
    for (int pos = 0; pos < 49; pos++) outp[pos * 256 + t] = buf[pos * 257 + t];
    return;
  }
  if (bid < 1336) {
    fmap_body64(bid - 1000, buf, p3, p4, p5, fmapT);
    return;
  }
  // ---- small converts (r3-proven body) ----
  const int i = (bid - 1336) * 256 + t;
  if (i < 262144) {
    const float4 v = ((const float4*)conv2_w)[i];
    half4v o = {(f16)v.x, (f16)v.y, (f16)v.z, (f16)v.w};
    ((half4v*)w2t)[i] = o;
  } else if (i < 262144 + 131072) {
    const int idx4 = i - 262144;
    const int elem = idx4 * 4;
    const int row = elem >> 10, col = elem & 1023;
    half4v o;
#pragma unroll
    for (int j = 0; j < 4; j++) {
      float v = 0.f;
      if (row < 81) v = lw[row * 1024 + col + j];
      else if (row < 405) v = bw[(row - 81) * 1024 + col + j];
      o[j] = (f16)v;
    }
    ((half4v*)wcat)[idx4] = o;
  } else if (i < 262144 + 131072 + 128) {
    const int j = (i - 393216) * 4;
    float r_[4];
#pragma unroll
    for (int q = 0; q < 4; q++) {
      const int c = j + q;
      float bv = 0.f;
      if (c < 81) bv = lb[c];
      else if (c < 405) bv = bb[c - 81];
      r_[q] = bv;
    }
    float4 o;
    o.x = r_[0]; o.y = r_[1]; o.z = r_[2]; o.w = r_[3];
    *(float4*)&bcat[j] = o;
  }
}

// ---- roi normal path v5 (r13-proven): 2 blocks/roi, batched-16-load ILP ----
__global__ __launch_bounds__(256) void roi_norm_k(const float* __restrict__ rois,
                                                  const f16* __restrict__ fmapT,
                                                  f16* __restrict__ pooled) {
  const int bid = blockIdx.x;
  const int r = bid >> 1, h = bid & 1;
  const int t = threadIdx.x;
  const int npos = h ? 24 : 25;
  const int pbase = h ? 25 : 0;
  if (r >= 1000) {
    f16* outp = pooled + (size_t)r * 12544 + t;
    for (int i = 0; i < npos; i++) outp[(pbase + i) * 256] = (f16)0.f;
    return;
  }
  __shared__ int s_lo[14], s_hi[14], s_val[14];
  __shared__ float s_w[14];
  __shared__ int q00[25], q01[25], q10[25], q11[25], qv[25];
  __shared__ float qwx[25], qwy[25];
  const float x1 = rois[r * 4 + 0], y1 = rois[r * 4 + 1];
  const float x2 = rois[r * 4 + 2], y2 = rois[r * 4 + 3];
  const float s = sqrtf(fmaxf((y2 - y1) * (x2 - x1), 0.f));
  const float lf = logf(s / 224.0f) / 0.69314718055994531f;
  int lv = (int)rintf(lf) + 4;
  lv = lv < 2 ? 2 : (lv > 5 ? 5 : lv);
  const int li = lv - 2;
  if (li == 0) return;  // level-2 handled in rest_prep_k
  const int H = 256 >> li;
  const int off = (li == 1) ? 0 : (li == 2) ? 16384 : 20480;
  const float Hm1 = (float)(H - 1);
  if (t < 14) {
    const bool isx = t >= 7;
    const int i = isx ? t - 7 : t;
    const float b1 = (isx ? x1 : y1) * (1.0f / 1024.0f);
    const float b2 = (isx ? x2 : y2) * (1.0f / 1024.0f);
    const float g = (float)i / 6.0f;
    const float coord = b1 * Hm1 + g * ((b2 - b1) * Hm1);
    const int valid = (coord >= 0.f) && (coord <= Hm1);
    float c = fminf(fmaxf(coord, 0.f), Hm1);
    float lo = floorf(c);
    s_lo[t] = (int)lo;
    s_hi[t] = (int)fminf(lo + 1.f, Hm1);
    s_w[t] = c - lo;
    s_val[t] = valid;
  }
  __syncthreads();
  if (t < npos) {
    const int pos = pbase + t;
    const int py = pos / 7, px = pos - py * 7;
    q00[t] = (s_lo[py] * H + s_lo[7 + px]) * 256;
    q01[t] = (s_lo[py] * H + s_hi[7 + px]) * 256;
    q10[t] = (s_hi[py] * H + s_lo[7 + px]) * 256;
    q11[t] = (s_hi[py] * H + s_hi[7 + px]) * 256;
    qwx[t] = s_w[7 + px];
    qwy[t] = s_w[py];
    qv[t] = s_val[py] && s_val[7 + px];
  }
  __syncthreads();
  const int c8 = (t & 31) * 8;
  const int g = t >> 5;
  const f16* base = fmapT + (size_t)off * 256 + c8;
  f16* outp = pooled + (size_t)r * 12544 + c8;
  int o00[4], o01[4], o10[4], o11[4], pw[4], ok[4], act[4];
  float wx[4], wy[4];
#pragma unroll
  for (int i = 0; i < 4; i++) {
    const int j = g + i * 8;
    act[i] = (j < npos);
    const int jj = act[i] ? j : 0;
    o00[i] = q00[jj]; o01[i] = q01[jj]; o10[i] = q10[jj]; o11[i] = q11[jj];
    wx[i] = qwx[jj]; wy[i] = qwy[jj]; ok[i] = qv[jj];
    pw[i] = (pbase + jj) * 256;
  }
  half8 v00[4], v01[4], v10[4], v11[4];
#pragma unroll
  for (int i = 0; i < 4; i++) {
    v00[i] = *(const half8*)&base[o00[i]];
    v01[i] = *(const half8*)&base[o01[i]];
    v10[i] = *(const half8*)&base[o10[i]];
    v11[i] = *(const half8*)&base[o11[i]];
  }
  __builtin_amdgcn_sched_barrier(0);
#pragma unroll
  for (int i = 0; i < 4; i++) {
    if (act[i]) {
      half8 o;
#pragma unroll
      for (int q = 0; q < 8; q++) {
        const float top = (float)v00[i][q] * (1.f - wx[i]) + (float)v01[i][q] * wx[i];
        const float bot = (float)v10[i][q] * (1.f - wx[i]) + (float)v11[i][q] * wx[i];
        float vvq = top * (1.f - wy[i]) + bot * wy[i];
        if (!ok[i]) vvq = 0.f;
        o[q] = (f16)vvq;
      }
      *(half8*)&outp[pw[i]] = o;
    }
  }
}

// ---- GEMM1 engine v2 (r5-proven): 8-wave 256x128, BK=32, 4-slot ring ----
// fp16 partials: parth[z][1024][1024].
__global__ __launch_bounds__(512) void gemm1_d2(
    const f16* __restrict__ A, const f16* __restrict__ B, f16* __restrict__ parth,
    int K, int kPerSplit) {
  __shared__ __align__(16) f16 As[4][256 * 32];   // 64 KB
  __shared__ __align__(16) f16 Bs[4][128 * 32];   // 32 KB
  const int t = threadIdx.x;

  int lid = blockIdx.x + 8 * (blockIdx.y + 4 * blockIdx.z);
  const int chunk = (8 * 4 * (int)gridDim.z) >> 3;
  lid = (lid & 7) * chunk + (lid >> 3);
  const int bx = lid & 7;
  const int by = (lid >> 3) & 3;
  const int bz = lid >> 5;

  const int m0 = by * 256, n0 = bx * 128;
  const int wid = t >> 6, lane = t & 63;
  const int wr = (wid & 3) * 64;   // 4 M-waves
  const int wc = (wid >> 2) * 64;  // 2 N-waves
  const int lrow = lane & 15;
  const int lsl = lane >> 4;
  const int srow = t >> 2;                              // 0..127 staging row
  const int scol = (((t & 3) ^ ((t >> 3) & 3)) << 3);   // pre-swizzled source slot
  const int kz0 = bz * kPerSplit;
  const int nIter = kPerSplit >> 5;

  f32x4 acc[4][4] = {};
  const f16* Ab = A + (size_t)(m0 + srow) * K + kz0 + scol;
  const f16* Bb = B + (size_t)(n0 + srow) * K + kz0 + scol;
  f16* asb = &As[0][0] + wid * 512;  // wave-uniform base within slot
  f16* bsb = &Bs[0][0] + wid * 512;

#define STG(kt) do {                                                           \
    const int sl_ = (kt) & 3; const size_t ko_ = (size_t)(kt) * 32;            \
    gload16(Ab + ko_, asb + sl_ * 8192);                                       \
    gload16(Ab + (size_t)128 * K + ko_, asb + sl_ * 8192 + 4096);              \
    gload16(Bb + ko_, bsb + sl_ * 4096);                                       \
    __builtin_amdgcn_sched_barrier(0);                                         \
  } while (0)

  STG(0);
  STG(1);
  asm volatile("s_waitcnt vmcnt(3)" ::: "memory");  // tile 0 resident
  __builtin_amdgcn_sched_barrier(0);
  __builtin_amdgcn_s_barrier();

  for (int kt = 0; kt < nIter; ++kt) {
    const int sl = kt & 3;
    const f16* as = &As[sl][0];
    const f16* bs = &Bs[sl][0];
    half8 aF[4], bF[4];
#pragma unroll
    for (int m = 0; m < 4; m++) {
      const int r_ = wr + m * 16 + lrow;
      aF[m] = *(const half8*)&as[r_ * 32 + ((lsl ^ ((r_ >> 1) & 3)) << 3)];
    }
#pragma unroll
    for (int n = 0; n < 4; n++) {
      const int r_ = wc + n * 16 + lrow;
      bF[n] = *(const half8*)&bs[r_ * 32 + ((lsl ^ ((r_ >> 1) & 3)) << 3)];
    }
    if (kt + 2 < nIter) STG(kt + 2);
    __builtin_amdgcn_s_setprio(1);
#pragma unroll
    for (int m = 0; m < 4; m++)
#pragma unroll
      for (int n = 0; n < 4; n++)
        acc[m][n] = __builtin_amdgcn_mfma_f32_16x16x32_f16(aF[m], bF[n], acc[m][n], 0, 0, 0);
    __builtin_amdgcn_s_setprio(0);
    if (kt + 2 < nIter) { asm volatile("s_waitcnt vmcnt(3)" ::: "memory"); }
    else                { asm volatile("s_waitcnt vmcnt(0)" ::: "memory"); }
    __builtin_amdgcn_sched_barrier(0);
    __builtin_amdgcn_s_barrier();
  }
#undef STG

  f16* outp = parth + (size_t)bz * (1024 * 1024);
#pragma unroll
  for (int m = 0; m < 4; m++) {
    const int rr = m0 + wr + m * 16 + lsl * 4;
#pragma unroll
    for (int n = 0; n < 4; n++) {
      const int cc = n0 + wc + n * 16 + lrow;
#pragma unroll
      for (int j = 0; j < 4; j++)
        outp[(size_t)(rr + j) * 1024 + cc] = (f16)acc[m][n][j];
    }
  }
}

// ---- GEMM2/3 engine (r3-proven): 3-buffer pipeline, fp32 partials ----
__global__ __launch_bounds__(256) void gemm_nt_p3(
    const f16* __restrict__ A, const f16* __restrict__ B, float* __restrict__ part,
    int K, int kPerSplit, int ldc) {
  __shared__ __align__(16) f16 As[3][128 * 32];
  __shared__ __align__(16) f16 Bs[3][128 * 32];
  const int t = threadIdx.x;

  const int gx = gridDim.x, gy = gridDim.y;
  int lid = blockIdx.x + gx * (blockIdx.y + gy * blockIdx.z);
  const int chunk = (gx * gy * (int)gridDim.z) >> 3;
  lid = (lid & 7) * chunk + (lid >> 3);
  const int bx = lid % gx;
  const int tmp = lid / gx;
  const int by = tmp % gy;
  const int bz = tmp / gy;

  const int m0 = by * 128;
  const int n0 = bx * 128;
  const int wid = t >> 6;
  const int lane = t & 63;
  const int wr = (wid >> 1) * 64;
  const int wc = (wid & 1) * 64;
  const int lrow = lane & 15;
  const int lsl = lane >> 4;
  const int rowA = t >> 2;
  const int c8 = (((t & 3) ^ ((rowA >> 1) & 3)) << 3);
  const int kz0 = bz * kPerSplit;
  const int nIter = kPerSplit >> 5;

  f32x4 acc[4][4] = {};
  const f16* Ab = A + (size_t)m0 * K + kz0 + c8;
  const f16* Bb = B + (size_t)n0 * K + kz0 + c8;

#define STAGE(buf, it)                                                        \
  do {                                                                        \
    const int ko = (it) * 32;                                                 \
    gload16(Ab + (size_t)rowA * K + ko, &As[buf][wid * 512]);                 \
    gload16(Ab + (size_t)(rowA + 64) * K + ko, &As[buf][2048 + wid * 512]);   \
    gload16(Bb + (size_t)rowA * K + ko, &Bs[buf][wid * 512]);                 \
    gload16(Bb + (size_t)(rowA + 64) * K + ko, &Bs[buf][2048 + wid * 512]);   \
  } while (0)

#define COMPUTE(buf)                                                          \
  do {                                                                        \
    half8 aF[4], bF[4];                                                       \
    _Pragma("unroll") for (int m = 0; m < 4; m++) {                           \
      const int rr_ = wr + m * 16 + lrow;                                     \
      aF[m] = *(const half8*)&As[buf][rr_ * 32 + ((lsl ^ ((rr_ >> 1) & 3)) << 3)]; \
    }                                                                         \
    _Pragma("unroll") for (int n = 0; n < 4; n++) {                           \
      const int rr_ = wc + n * 16 + lrow;                                     \
      bF[n] = *(const half8*)&Bs[buf][rr_ * 32 + ((lsl ^ ((rr_ >> 1) & 3)) << 3)]; \
    }                                                                         \
    __builtin_amdgcn_s_setprio(1);                                            \
    _Pragma("unroll") for (int m = 0; m < 4; m++)                             \
      _Pragma("unroll") for (int n = 0; n < 4; n++)                           \
        acc[m][n] = __builtin_amdgcn_mfma_f32_16x16x32_f16(aF[m], bF[n], acc[m][n], 0, 0, 0); \
    __builtin_amdgcn_s_setprio(0);                                            \
  } while (0)

  STAGE(0, 0);
  STAGE(1, 1);
  int bc = 0;
  for (int it = 0; it < nIter - 2; ++it) {
    const int bs_ = (bc == 0) ? 2 : bc - 1;
    STAGE(bs_, it + 2);
    asm volatile("s_waitcnt vmcnt(8)" ::: "memory");
    __builtin_amdgcn_sched_barrier(0);
    __builtin_amdgcn_s_barrier();
    COMPUTE(bc);
    __builtin_amdgcn_s_barrier();
    bc = (bc == 2) ? 0 : bc + 1;
  }
  asm volatile("s_waitcnt vmcnt(4)" ::: "memory");
  __builtin_amdgcn_sched_barrier(0);
  __builtin_amdgcn_s_barrier();
  COMPUTE(bc);
  __builtin_amdgcn_s_barrier();
  bc = (bc == 2) ? 0 : bc + 1;
  asm volatile("s_waitcnt vmcnt(0)" ::: "memory");
  __builtin_amdgcn_sched_barrier(0);
  __builtin_amdgcn_s_barrier();
  COMPUTE(bc);
#undef STAGE
#undef COMPUTE

  const size_t slice = (size_t)gy * 128 * ldc;
#pragma unroll
  for (int m = 0; m < 4; m++) {
#pragma unroll
    for (int n = 0; n < 4; n++) {
#pragma unroll
      for (int j = 0; j < 4; j++) {
        const int rr = m0 + wr + m * 16 + ((lane >> 4) << 2) + j;
        const int cc = n0 + wc + n * 16 + (lane & 15);
        part[(size_t)bz * slice + (size_t)rr * ldc + cc] = acc[m][n][j];
      }
    }
  }
}

// ---- reduce GEMM1 fp16 partials: 8 slices + bias + bn1 + relu -> f16 ----
__global__ void reduce1h_k(const f16* __restrict__ parth, const float* __restrict__ bias,
                           const float* __restrict__ g, const float* __restrict__ b,
                           const float* __restrict__ m, const float* __restrict__ v,
                           f16* __restrict__ out) {
  const int i4 = (blockIdx.x * 256 + threadIdx.x) * 4;
  float s[4] = {0.f, 0.f, 0.f, 0.f};
#pragma unroll
  for (int z = 0; z < 8; z++) {
    const half4v p = *(const half4v*)(parth + (size_t)z * 1048576 + i4);
#pragma unroll
    for (int j = 0; j < 4; j++) s[j] += (float)p[j];
  }
  const int c0 = i4 & 1023;
  half4v o;
#pragma unroll
  for (int j = 0; j < 4; j++) {
    const int c = c0 + j;
    const float x = s[j] + bias[c];
    const float sc = g[c] / sqrtf(v[c] + 1e-3f);
    o[j] = (f16)fmaxf((x - m[c]) * sc + b[c], 0.f);
  }
  *(half4v*)(out + i4) = o;
}

// ---- split-K reduce + epilogue (fp32 partials): bias+BN+ReLU->f16 ----
template <int Z>
__global__ void reduce_ep_k(const float* __restrict__ part, int sliceE, int ldc,
                            const float* __restrict__ bias, const float* __restrict__ g,
                            const float* __restrict__ b, const float* __restrict__ m,
                            const float* __restrict__ v, f16* __restrict__ out) {
  const int i4 = (blockIdx.x * 256 + threadIdx.x) * 4;
  float4 s = *(const float4*)(part + i4);
#pragma unroll
  for (int z = 1; z < Z; z++) {
    const float4 p = *(const float4*)(part + (size_t)z * sliceE + i4);
    s.x += p.x; s.y += p.y; s.z += p.z; s.w += p.w;
  }
  const int c0 = i4 % ldc;
  float r[4] = {s.x, s.y, s.z, s.w};
  half4v o;
#pragma unroll
  for (int j = 0; j < 4; j++) {
    const int c = c0 + j;
    const float x = r[j] + bias[c];
    const float sc = g[c] / sqrtf(v[c] + 1e-3f);
    o[j] = (f16)fmaxf((x - m[c]) * sc + b[c], 0.f);
  }
  *(half4v*)(out + i4) = o;
}

// ---- fused: reduce GEMM3 partials (8 slices) + bias + softmax + scatter ----
__global__ __launch_bounds__(256) void reduce3_out_k(const float* __restrict__ part,
                                                     const float* __restrict__ bcat,
                                                     float* __restrict__ out) {
  const int r = blockIdx.x, t = threadIdx.x;
  __shared__ float red[256];
  const float* base = part + (size_t)r * 512;
  float v0 = 0.f, v1 = 0.f;
  {
    float s = bcat[t];
#pragma unroll
    for (int z = 0; z < 8; z++) s += base[(size_t)z * 524288 + t];
    v0 = s;
  }
  if (t < 149) {
    float s = bcat[256 + t];
#pragma unroll
    for (int z = 0; z < 8; z++) s += base[(size_t)z * 524288 + 256 + t];
    v1 = s;
  }
  red[t] = (t < 81) ? v0 : -INFINITY;
  __syncthreads();
  for (int s_ = 128; s_ > 0; s_ >>= 1) {
    if (t < s_) red[t] = fmaxf(red[t], red[t + s_]);
    __syncthreads();
  }
  const float mx = red[0];
  __syncthreads();
  const float e = (t < 81) ? expf(v0 - mx) : 0.f;
  red[t] = e;
  __syncthreads();
  for (int s_ = 128; s_ > 0; s_ >>= 1) {
    if (t < s_) red[t] += red[t + s_];
    __syncthreads();
  }
  const float inv = 1.f / red[0];
  if (t < 81) {
    out[(size_t)r * 81 + t] = v0;
    out[81000 + (size_t)r * 81 + t] = e * inv;
  }
  if (t >= 81) out[162000 + (size_t)r * 324 + (t - 81)] = v0;
  if (t < 149) out[162000 + (size_t)r * 324 + 175 + t] = v1;
}

extern "C" void kernel_launch(void* const* d_in, const int* in_sizes, int n_in,
                              void* d_out, int out_size, void* d_ws, size_t ws_size,
                              hipStream_t stream) {
  const float* p2 = (const float*)d_in[0];
  const float* p3 = (const float*)d_in[1];
  const float* p4 = (const float*)d_in[2];
  const float* p5 = (const float*)d_in[3];
  const float* rois = (const float*)d_in[4];
  const float* conv1_w = (const float*)d_in[5];
  const float* conv1_b = (const float*)d_in[6];
  const float* bn1_g = (const float*)d_in[7];
  const float* bn1_b = (const float*)d_in[8];
  const float* bn1_m = (const float*)d_in[9];
  const float* bn1_v = (const float*)d_in[10];
  const float* conv2_w = (const float*)d_in[11];
  const float* conv2_b = (const float*)d_in[12];
  const float* bn2_g = (const float*)d_in[13];
  const float* bn2_b = (const float*)d_in[14];
  const float* bn2_m = (const float*)d_in[15];
  const float* bn2_v = (const float*)d_in[16];
  const float* logits_w = (const float*)d_in[17];
  const float* logits_b = (const float*)d_in[18];
  const float* bbox_w = (const float*)d_in[19];
  const float* bbox_b = (const float*)d_in[20];

  char* ws = (char*)d_ws;
  f16* sh1 = (f16*)(ws + (size_t)0);
  f16* sh2 = (f16*)(ws + ((size_t)2 << 20));
  f16* w2t = (f16*)(ws + ((size_t)6 << 20));
  f16* wcat = (f16*)(ws + ((size_t)8 << 20));
  float* bcat = (float*)(ws + ((size_t)9 << 20));
  f16* fmapT = (f16*)(ws + (size_t)9961472);   // 9.5MB (dead after roi)
  f16* parth = (f16*)(ws + ((size_t)10 << 20));
  float* part = (float*)(ws + ((size_t)10 << 20));
  f16* pooled = (f16*)(ws + (size_t)44564480);
  f16* w1t = (f16*)(ws + (size_t)70254592);

  // 1a) streaming w1 repack ALONE (fast pattern isolated)
  w1t_only_k<<<1024, 256, 0, stream>>>(conv1_w, w1t);
  // 1b) gather + fmap(64px) + small converts
  rest_prep_k<<<2873, 256, 0, stream>>>(p2, p3, p4, p5, rois, conv2_w,
                                        logits_w, logits_b, bbox_w, bbox_b,
                                        fmapT, pooled, w2t, wcat, bcat);
  // 2) roi normal path: 2 blocks/roi, batched-load ILP
  roi_norm_k<<<2048, 256, 0, stream>>>(rois, fmapT, pooled);
  // 3) GEMM1: split-K=8, deep-pipeline engine, fp16 partials
  gemm1_d2<<<dim3(8, 4, 8), 512, 0, stream>>>(pooled, w1t, parth, 12544, 1568);
  reduce1h_k<<<1024, 256, 0, stream>>>(parth, conv1_b, bn1_g, bn1_b, bn1_m,
                                       bn1_v, sh1);
  // 4) GEMM2: split-K=4 (fp32 partials reuse part region)
  gemm_nt_p3<<<dim3(8, 8, 4), 256, 0, stream>>>(sh1, w2t, part, 1024, 256, 1024);
  reduce_ep_k<4><<<1024, 256, 0, stream>>>(part, 1048576, 1024, conv2_b, bn2_g,
                                           bn2_b, bn2_m, bn2_v, sh2);
  // 5) GEMM3: split-K=8
  gemm_nt_p3<<<dim3(4, 8, 8), 256, 0, stream>>>(sh2, wcat, part, 1024, 128, 512);
  // 6) fused reduce3 + softmax + output scatter
  reduce3_out_k<<<1000, 256, 0, stream>>>(part, bcat, (float*)d_out);
}

// Round 21
// 110.968 us; speedup vs baseline: 1.1242x; 1.1242x over previous
//
#include <hip/hip_runtime.h>
#include <hip/hip_fp16.h>
#include <math.h>

typedef _Float16 f16;
typedef _Float16 half8 __attribute__((ext_vector_type(8)));
typedef _Float16 half4v __attribute__((ext_vector_type(4)));
typedef _Float16 half2v __attribute__((ext_vector_type(2)));
typedef float f32x4 __attribute__((ext_vector_type(4)));

// ---------------- ws layout (bytes) ----------------
// sh1  @ 0MB   fp16 [1024][1024]
// sh2  @ 2MB   fp16 [1024][1024]
// w2t  @ 6MB   fp16 [1024][1024]
// wcat @ 8MB   fp16 [512][1024]
// bcat @ 9MB   fp32 [512]
// fmapT@ 9.5MB fp16 [21504][256]  (levels 3,4,5 at px 0,16384,20480) ends 20MB
// part @ 10MB  gemm1: f16 [8][1024][1024]=16MB; gemm2/3: fp32 (reused), ends 42MB
// pooled @ 44,564,480  fp16 [1024][49*256]
// w1t    @ 70,254,592  fp16 [1024][49*256]   (total 95,944,704 B)

__device__ __forceinline__ void gload16(const void* g, void* lds) {
  __builtin_amdgcn_global_load_lds(
      (const __attribute__((address_space(1))) unsigned int*)g,
      (__attribute__((address_space(3))) unsigned int*)lds, 16, 0, 0);
}

// ======== prep bodies ========
__device__ __forceinline__ void fmap_body64(int b, f16* tile,
                                            const float* __restrict__ p3,
                                            const float* __restrict__ p4,
                                            const float* __restrict__ p5,
                                            f16* __restrict__ dst0) {
  const float* src;
  int Ppix, p0;
  size_t dstoff;
  if (b < 256)      { src = p3; Ppix = 16384; dstoff = 0;     p0 = b * 64; }
  else if (b < 320) { src = p4; Ppix = 4096;  dstoff = 16384; p0 = (b - 256) * 64; }
  else              { src = p5; Ppix = 1024;  dstoff = 20480; p0 = (b - 320) * 64; }
  const int t = threadIdx.x;
  const int px4 = (t & 15) * 4;   // 0..60
  const int cp = (t >> 4) * 2;    // 0..30
#pragma unroll
  for (int i = 0; i < 8; i++) {
    const int c = i * 32 + cp;
    const float4 va = *(const float4*)&src[(size_t)c * Ppix + p0 + px4];
    const float4 vb = *(const float4*)&src[(size_t)(c + 1) * Ppix + p0 + px4];
    const float a_[4] = {va.x, va.y, va.z, va.w};
    const float b_[4] = {vb.x, vb.y, vb.z, vb.w};
#pragma unroll
    for (int j = 0; j < 4; j++) {
      const int px = px4 + j;
      const int cs = c ^ (((px >> 2) & 31) << 3);  // flips bits>=3, parity kept
      half2v h = {(f16)a_[j], (f16)b_[j]};
      *(half2v*)&tile[px * 256 + cs] = h;
    }
  }
  __syncthreads();
  f16* d = dst0 + (dstoff + (size_t)p0) * 256;
  const int c8 = (t & 31) * 8;
  const int pxw = t >> 5;  // 0..7
#pragma unroll
  for (int i = 0; i < 8; i++) {
    const int px = i * 8 + pxw;
    const int c8s = c8 ^ (((px >> 2) & 31) << 3);
    const half8 o = *(const half8*)&tile[px * 256 + c8s];
    *(half8*)&d[px * 256 + c8] = o;
  }
}

// w1 repack v3 (r16-proven): phase-1 via global_load_lds.
// buf layout: raw fp32 [6272] at buf[0] (25,088B); tile f16 [49*260] at buf+12544.
__device__ __forceinline__ void w1t_body(int k, f16* buf,
                                         const float* __restrict__ w1,
                                         f16* __restrict__ w1t) {
  const int t = threadIdx.x;
  float* raw = (float*)buf;
  f16* tile = buf + 12544;
  const float* src = w1 + (size_t)k * 12544;
  f16* dst = w1t + (size_t)k * 12544;
#pragma unroll
  for (int h = 0; h < 2; h++) {
    const float* sh_ = src + h * 6272;   // c in [128h, 128h+128): 6272 floats
#pragma unroll
    for (int j = 0; j < 6; j++)
      gload16(sh_ + (size_t)(j * 256 + t) * 4, raw + (size_t)(j * 256 + t) * 4);
    float4 tail;
    if (t < 32) tail = *(const float4*)&sh_[(1536 + t) * 4];
    asm volatile("s_waitcnt vmcnt(0)" ::: "memory");
    __builtin_amdgcn_sched_barrier(0);
    if (t < 32) *(float4*)&raw[(1536 + t) * 4] = tail;
    __syncthreads();
#pragma unroll
    for (int i = 0; i < 25; i++) {
      const int v = i * 256 + t;
      if (v < 6272) {
        const int c = v / 49, pq = v - c * 49;
        tile[pq * 260 + (h * 128 + c)] = (f16)raw[v];
      }
    }
    __syncthreads();
  }
#pragma unroll
  for (int i = 0; i < 7; i++) {
    const int h8 = i * 256 + t;
    if (h8 < 1568) {
      const int pq = h8 >> 5, c8 = (h8 & 31) * 8;
      const half4v lo = *(const half4v*)&tile[pq * 260 + c8];
      const half4v hi = *(const half4v*)&tile[pq * 260 + c8 + 4];
      half8 o;
      o[0] = lo[0]; o[1] = lo[1]; o[2] = lo[2]; o[3] = lo[3];
      o[4] = hi[0]; o[5] = hi[1]; o[6] = hi[2]; o[7] = hi[3];
      *(half8*)&dst[pq * 256 + c8] = o;
    }
  }
}

// grid = 6905: [0,4000) gather (4 blocks/roi, 64ch each); [4000,5368) {1 fmap :
// 3 w1t} groups; [5368,6905) small converts.
__global__ __launch_bounds__(256) void prep_all_k(
    const float* __restrict__ p2, const float* __restrict__ p3,
    const float* __restrict__ p4, const float* __restrict__ p5,
    const float* __restrict__ conv1_w, const float* __restrict__ rois,
    const float* __restrict__ conv2_w, const float* __restrict__ lw,
    const float* __restrict__ lb, const float* __restrict__ bw,
    const float* __restrict__ bb, f16* __restrict__ fmapT,
    f16* __restrict__ w1t, f16* __restrict__ pooled, f16* __restrict__ w2t,
    f16* __restrict__ wcat, float* __restrict__ bcat) {
  __shared__ __align__(16) f16 buf[25600];  // 50 KB union
  const int bid = blockIdx.x;
  const int t = threadIdx.x;
  if (bid < 4000) {
    // ---- level-2 gather v4: 4 blocks/roi, 64 channels each ----
    const int r = bid >> 2, q = bid & 3;
    const float x1 = rois[r * 4 + 0], y1 = rois[r * 4 + 1];
    const float x2 = rois[r * 4 + 2], y2 = rois[r * 4 + 3];
    const float s = sqrtf(fmaxf((y2 - y1) * (x2 - x1), 0.f));
    const float lf = logf(s / 224.0f) / 0.69314718055994531f;
    int lv = (int)rintf(lf) + 4;
    lv = lv < 2 ? 2 : (lv > 5 ? 5 : lv);
    if (lv != 2) return;
    const int wid = t >> 6, lane = t & 63;
    const float Hm1 = 255.f;
    int o00 = 0, o01 = 0, o10 = 0, o11 = 0;
    float wxl = 0.f, wyl = 0.f;
    bool vv = false;
    if (lane < 49) {
      const int py = lane / 7, px = lane % 7;
      const float y1n = y1 * (1.0f / 1024.0f), y2n = y2 * (1.0f / 1024.0f);
      const float x1n = x1 * (1.0f / 1024.0f), x2n = x2 * (1.0f / 1024.0f);
      const float cyc = y1n * Hm1 + ((float)py / 6.0f) * ((y2n - y1n) * Hm1);
      const float cxc = x1n * Hm1 + ((float)px / 6.0f) * ((x2n - x1n) * Hm1);
      const bool vy = (cyc >= 0.f) && (cyc <= Hm1);
      const bool vx = (cxc >= 0.f) && (cxc <= Hm1);
      float cy = fminf(fmaxf(cyc, 0.f), Hm1);
      float cx = fminf(fmaxf(cxc, 0.f), Hm1);
      const float fy = floorf(cy), fx = floorf(cx);
      const int ylo = (int)fy, xlo = (int)fx;
      const int yhi = (int)fminf(fy + 1.f, Hm1);
      const int xhi = (int)fminf(fx + 1.f, Hm1);
      wyl = cy - fy;
      wxl = cx - fx;
      vv = vy && vx;
      o00 = ylo * 256 + xlo;
      o01 = ylo * 256 + xhi;
      o10 = yhi * 256 + xlo;
      o11 = yhi * 256 + xhi;
    }
    // 16 iterations (was 64): wave wid covers local channels wid, wid+4, ...
#pragma unroll 4
    for (int ci = 0; ci < 16; ci++) {
      const int chL = ci * 4 + wid;  // local channel 0..63
      const float* pc = p2 + (size_t)(q * 64 + chL) * 65536;
      if (lane < 49) {
        const float v00 = pc[o00], v01 = pc[o01];
        const float v10 = pc[o10], v11 = pc[o11];
        const float top = v00 * (1.f - wxl) + v01 * wxl;
        const float bot = v10 * (1.f - wxl) + v11 * wxl;
        float val = top * (1.f - wyl) + bot * wyl;
        if (!vv) val = 0.f;
        buf[lane * 257 + chL] = (f16)val;
      }
    }
    __syncthreads();
    // write 49 pos x 64 ch slice: idx = pos*64 + c
    f16* outp = pooled + (size_t)r * 12544 + q * 64;
#pragma unroll
    for (int i = 0; i < 13; i++) {
      const int idx = i * 256 + t;
      if (idx < 3136) {
        const int pos = idx >> 6, c = idx & 63;
        outp[(size_t)pos * 256 + c] = buf[pos * 257 + c];
      }
    }
    return;
  }
  if (bid < 5368) {
    const int b2 = bid - 4000;
    const int g = b2 >> 2, rr = b2 & 3;
    if (rr == 0) {
      if (g < 336) fmap_body64(g, buf, p3, p4, p5, fmapT);
    } else {
      const int wb = g * 3 + (rr - 1);
      if (wb < 1024) w1t_body(wb, buf, conv1_w, w1t);
    }
    return;
  }
  // ---- small converts (r3-proven body) ----
  const int i = (bid - 5368) * 256 + t;
  if (i < 262144) {
    const float4 v = ((const float4*)conv2_w)[i];
    half4v o = {(f16)v.x, (f16)v.y, (f16)v.z, (f16)v.w};
    ((half4v*)w2t)[i] = o;
  } else if (i < 262144 + 131072) {
    const int idx4 = i - 262144;
    const int elem = idx4 * 4;
    const int row = elem >> 10, col = elem & 1023;
    half4v o;
#pragma unroll
    for (int j = 0; j < 4; j++) {
      float v = 0.f;
      if (row < 81) v = lw[row * 1024 + col + j];
      else if (row < 405) v = bw[(row - 81) * 1024 + col + j];
      o[j] = (f16)v;
    }
    ((half4v*)wcat)[idx4] = o;
  } else if (i < 262144 + 131072 + 128) {
    const int j = (i - 393216) * 4;
    float r_[4];
#pragma unroll
    for (int q = 0; q < 4; q++) {
      const int c = j + q;
      float bv = 0.f;
      if (c < 81) bv = lb[c];
      else if (c < 405) bv = bb[c - 81];
      r_[q] = bv;
    }
    float4 o;
    o.x = r_[0]; o.y = r_[1]; o.z = r_[2]; o.w = r_[3];
    *(float4*)&bcat[j] = o;
  }
}

// ---- roi normal path v5 (r13-proven): 2 blocks/roi, batched-16-load ILP ----
__global__ __launch_bounds__(256) void roi_norm_k(const float* __restrict__ rois,
                                                  const f16* __restrict__ fmapT,
                                                  f16* __restrict__ pooled) {
  const int bid = blockIdx.x;
  const int r = bid >> 1, h = bid & 1;
  const int t = threadIdx.x;
  const int npos = h ? 24 : 25;
  const int pbase = h ? 25 : 0;
  if (r >= 1000) {
    f16* outp = pooled + (size_t)r * 12544 + t;
    for (int i = 0; i < npos; i++) outp[(pbase + i) * 256] = (f16)0.f;
    return;
  }
  __shared__ int s_lo[14], s_hi[14], s_val[14];
  __shared__ float s_w[14];
  __shared__ int q00[25], q01[25], q10[25], q11[25], qv[25];
  __shared__ float qwx[25], qwy[25];
  const float x1 = rois[r * 4 + 0], y1 = rois[r * 4 + 1];
  const float x2 = rois[r * 4 + 2], y2 = rois[r * 4 + 3];
  const float s = sqrtf(fmaxf((y2 - y1) * (x2 - x1), 0.f));
  const float lf = logf(s / 224.0f) / 0.69314718055994531f;
  int lv = (int)rintf(lf) + 4;
  lv = lv < 2 ? 2 : (lv > 5 ? 5 : lv);
  const int li = lv - 2;
  if (li == 0) return;  // level-2 handled in prep_all_k
  const int H = 256 >> li;
  const int off = (li == 1) ? 0 : (li == 2) ? 16384 : 20480;
  const float Hm1 = (float)(H - 1);
  if (t < 14) {
    const bool isx = t >= 7;
    const int i = isx ? t - 7 : t;
    const float b1 = (isx ? x1 : y1) * (1.0f / 1024.0f);
    const float b2 = (isx ? x2 : y2) * (1.0f / 1024.0f);
    const float g = (float)i / 6.0f;
    const float coord = b1 * Hm1 + g * ((b2 - b1) * Hm1);
    const int valid = (coord >= 0.f) && (coord <= Hm1);
    float c = fminf(fmaxf(coord, 0.f), Hm1);
    float lo = floorf(c);
    s_lo[t] = (int)lo;
    s_hi[t] = (int)fminf(lo + 1.f, Hm1);
    s_w[t] = c - lo;
    s_val[t] = valid;
  }
  __syncthreads();
  if (t < npos) {
    const int pos = pbase + t;
    const int py = pos / 7, px = pos - py * 7;
    q00[t] = (s_lo[py] * H + s_lo[7 + px]) * 256;
    q01[t] = (s_lo[py] * H + s_hi[7 + px]) * 256;
    q10[t] = (s_hi[py] * H + s_lo[7 + px]) * 256;
    q11[t] = (s_hi[py] * H + s_hi[7 + px]) * 256;
    qwx[t] = s_w[7 + px];
    qwy[t] = s_w[py];
    qv[t] = s_val[py] && s_val[7 + px];
  }
  __syncthreads();
  const int c8 = (t & 31) * 8;
  const int g = t >> 5;
  const f16* base = fmapT + (size_t)off * 256 + c8;
  f16* outp = pooled + (size_t)r * 12544 + c8;
  int o00[4], o01[4], o10[4], o11[4], pw[4], ok[4], act[4];
  float wx[4], wy[4];
#pragma unroll
  for (int i = 0; i < 4; i++) {
    const int j = g + i * 8;
    act[i] = (j < npos);
    const int jj = act[i] ? j : 0;
    o00[i] = q00[jj]; o01[i] = q01[jj]; o10[i] = q10[jj]; o11[i] = q11[jj];
    wx[i] = qwx[jj]; wy[i] = qwy[jj]; ok[i] = qv[jj];
    pw[i] = (pbase + jj) * 256;
  }
  half8 v00[4], v01[4], v10[4], v11[4];
#pragma unroll
  for (int i = 0; i < 4; i++) {
    v00[i] = *(const half8*)&base[o00[i]];
    v01[i] = *(const half8*)&base[o01[i]];
    v10[i] = *(const half8*)&base[o10[i]];
    v11[i] = *(const half8*)&base[o11[i]];
  }
  __builtin_amdgcn_sched_barrier(0);
#pragma unroll
  for (int i = 0; i < 4; i++) {
    if (act[i]) {
      half8 o;
#pragma unroll
      for (int q = 0; q < 8; q++) {
        const float top = (float)v00[i][q] * (1.f - wx[i]) + (float)v01[i][q] * wx[i];
        const float bot = (float)v10[i][q] * (1.f - wx[i]) + (float)v11[i][q] * wx[i];
        float vvq = top * (1.f - wy[i]) + bot * wy[i];
        if (!ok[i]) vvq = 0.f;
        o[q] = (f16)vvq;
      }
      *(half8*)&outp[pw[i]] = o;
    }
  }
}

// ---- GEMM1 engine v2 (r5-proven): 8-wave 256x128, BK=32, 4-slot ring ----
// fp16 partials: parth[z][1024][1024].
__global__ __launch_bounds__(512) void gemm1_d2(
    const f16* __restrict__ A, const f16* __restrict__ B, f16* __restrict__ parth,
    int K, int kPerSplit) {
  __shared__ __align__(16) f16 As[4][256 * 32];   // 64 KB
  __shared__ __align__(16) f16 Bs[4][128 * 32];   // 32 KB
  const int t = threadIdx.x;

  int lid = blockIdx.x + 8 * (blockIdx.y + 4 * blockIdx.z);
  const int chunk = (8 * 4 * (int)gridDim.z) >> 3;
  lid = (lid & 7) * chunk + (lid >> 3);
  const int bx = lid & 7;
  const int by = (lid >> 3) & 3;
  const int bz = lid >> 5;

  const int m0 = by * 256, n0 = bx * 128;
  const int wid = t >> 6, lane = t & 63;
  const int wr = (wid & 3) * 64;   // 4 M-waves
  const int wc = (wid >> 2) * 64;  // 2 N-waves
  const int lrow = lane & 15;
  const int lsl = lane >> 4;
  const int srow = t >> 2;                              // 0..127 staging row
  const int scol = (((t & 3) ^ ((t >> 3) & 3)) << 3);   // pre-swizzled source slot
  const int kz0 = bz * kPerSplit;
  const int nIter = kPerSplit >> 5;

  f32x4 acc[4][4] = {};
  const f16* Ab = A + (size_t)(m0 + srow) * K + kz0 + scol;
  const f16* Bb = B + (size_t)(n0 + srow) * K + kz0 + scol;
  f16* asb = &As[0][0] + wid * 512;  // wave-uniform base within slot
  f16* bsb = &Bs[0][0] + wid * 512;

#define STG(kt) do {                                                           \
    const int sl_ = (kt) & 3; const size_t ko_ = (size_t)(kt) * 32;            \
    gload16(Ab + ko_, asb + sl_ * 8192);                                       \
    gload16(Ab + (size_t)128 * K + ko_, asb + sl_ * 8192 + 4096);              \
    gload16(Bb + ko_, bsb + sl_ * 4096);                                       \
    __builtin_amdgcn_sched_barrier(0);                                         \
  } while (0)

  STG(0);
  STG(1);
  asm volatile("s_waitcnt vmcnt(3)" ::: "memory");  // tile 0 resident
  __builtin_amdgcn_sched_barrier(0);
  __builtin_amdgcn_s_barrier();

  for (int kt = 0; kt < nIter; ++kt) {
    const int sl = kt & 3;
    const f16* as = &As[sl][0];
    const f16* bs = &Bs[sl][0];
    half8 aF[4], bF[4];
#pragma unroll
    for (int m = 0; m < 4; m++) {
      const int r_ = wr + m * 16 + lrow;
      aF[m] = *(const half8*)&as[r_ * 32 + ((lsl ^ ((r_ >> 1) & 3)) << 3)];
    }
#pragma unroll
    for (int n = 0; n < 4; n++) {
      const int r_ = wc + n * 16 + lrow;
      bF[n] = *(const half8*)&bs[r_ * 32 + ((lsl ^ ((r_ >> 1) & 3)) << 3)];
    }
    if (kt + 2 < nIter) STG(kt + 2);
    __builtin_amdgcn_s_setprio(1);
#pragma unroll
    for (int m = 0; m < 4; m++)
#pragma unroll
      for (int n = 0; n < 4; n++)
        acc[m][n] = __builtin_amdgcn_mfma_f32_16x16x32_f16(aF[m], bF[n], acc[m][n], 0, 0, 0);
    __builtin_amdgcn_s_setprio(0);
    if (kt + 2 < nIter) { asm volatile("s_waitcnt vmcnt(3)" ::: "memory"); }
    else                { asm volatile("s_waitcnt vmcnt(0)" ::: "memory"); }
    __builtin_amdgcn_sched_barrier(0);
    __builtin_amdgcn_s_barrier();
  }
#undef STG

  f16* outp = parth + (size_t)bz * (1024 * 1024);
#pragma unroll
  for (int m = 0; m < 4; m++) {
    const int rr = m0 + wr + m * 16 + lsl * 4;
#pragma unroll
    for (int n = 0; n < 4; n++) {
      const int cc = n0 + wc + n * 16 + lrow;
#pragma unroll
      for (int j = 0; j < 4; j++)
        outp[(size_t)(rr + j) * 1024 + cc] = (f16)acc[m][n][j];
    }
  }
}

// ---- GEMM2/3 engine (r3-proven): 3-buffer pipeline, fp32 partials ----
__global__ __launch_bounds__(256) void gemm_nt_p3(
    const f16* __restrict__ A, const f16* __restrict__ B, float* __restrict__ part,
    int K, int kPerSplit, int ldc) {
  __shared__ __align__(16) f16 As[3][128 * 32];
  __shared__ __align__(16) f16 Bs[3][128 * 32];
  const int t = threadIdx.x;

  const int gx = gridDim.x, gy = gridDim.y;
  int lid = blockIdx.x + gx * (blockIdx.y + gy * blockIdx.z);
  const int chunk = (gx * gy * (int)gridDim.z) >> 3;
  lid = (lid & 7) * chunk + (lid >> 3);
  const int bx = lid % gx;
  const int tmp = lid / gx;
  const int by = tmp % gy;
  const int bz = tmp / gy;

  const int m0 = by * 128;
  const int n0 = bx * 128;
  const int wid = t >> 6;
  const int lane = t & 63;
  const int wr = (wid >> 1) * 64;
  const int wc = (wid & 1) * 64;
  const int lrow = lane & 15;
  const int lsl = lane >> 4;
  const int rowA = t >> 2;
  const int c8 = (((t & 3) ^ ((rowA >> 1) & 3)) << 3);
  const int kz0 = bz * kPerSplit;
  const int nIter = kPerSplit >> 5;

  f32x4 acc[4][4] = {};
  const f16* Ab = A + (size_t)m0 * K + kz0 + c8;
  const f16* Bb = B + (size_t)n0 * K + kz0 + c8;

#define STAGE(buf, it)                                                        \
  do {                                                                        \
    const int ko = (it) * 32;                                                 \
    gload16(Ab + (size_t)rowA * K + ko, &As[buf][wid * 512]);                 \
    gload16(Ab + (size_t)(rowA + 64) * K + ko, &As[buf][2048 + wid * 512]);   \
    gload16(Bb + (size_t)rowA * K + ko, &Bs[buf][wid * 512]);                 \
    gload16(Bb + (size_t)(rowA + 64) * K + ko, &Bs[buf][2048 + wid * 512]);   \
  } while (0)

#define COMPUTE(buf)                                                          \
  do {                                                                        \
    half8 aF[4], bF[4];                                                       \
    _Pragma("unroll") for (int m = 0; m < 4; m++) {                           \
      const int rr_ = wr + m * 16 + lrow;                                     \
      aF[m] = *(const half8*)&As[buf][rr_ * 32 + ((lsl ^ ((rr_ >> 1) & 3)) << 3)]; \
    }                                                                         \
    _Pragma("unroll") for (int n = 0; n < 4; n++) {                           \
      const int rr_ = wc + n * 16 + lrow;                                     \
      bF[n] = *(const half8*)&Bs[buf][rr_ * 32 + ((lsl ^ ((rr_ >> 1) & 3)) << 3)]; \
    }                                                                         \
    __builtin_amdgcn_s_setprio(1);                                            \
    _Pragma("unroll") for (int m = 0; m < 4; m++)                             \
      _Pragma("unroll") for (int n = 0; n < 4; n++)                           \
        acc[m][n] = __builtin_amdgcn_mfma_f32_16x16x32_f16(aF[m], bF[n], acc[m][n], 0, 0, 0); \
    __builtin_amdgcn_s_setprio(0);                                            \
  } while (0)

  STAGE(0, 0);
  STAGE(1, 1);
  int bc = 0;
  for (int it = 0; it < nIter - 2; ++it) {
    const int bs_ = (bc == 0) ? 2 : bc - 1;
    STAGE(bs_, it + 2);
    asm volatile("s_waitcnt vmcnt(8)" ::: "memory");
    __builtin_amdgcn_sched_barrier(0);
    __builtin_amdgcn_s_barrier();
    COMPUTE(bc);
    __builtin_amdgcn_s_barrier();
    bc = (bc == 2) ? 0 : bc + 1;
  }
  asm volatile("s_waitcnt vmcnt(4)" ::: "memory");
  __builtin_amdgcn_sched_barrier(0);
  __builtin_amdgcn_s_barrier();
  COMPUTE(bc);
  __builtin_amdgcn_s_barrier();
  bc = (bc == 2) ? 0 : bc + 1;
  asm volatile("s_waitcnt vmcnt(0)" ::: "memory");
  __builtin_amdgcn_sched_barrier(0);
  __builtin_amdgcn_s_barrier();
  COMPUTE(bc);
#undef STAGE
#undef COMPUTE

  const size_t slice = (size_t)gy * 128 * ldc;
#pragma unroll
  for (int m = 0; m < 4; m++) {
#pragma unroll
    for (int n = 0; n < 4; n++) {
#pragma unroll
      for (int j = 0; j < 4; j++) {
        const int rr = m0 + wr + m * 16 + ((lane >> 4) << 2) + j;
        const int cc = n0 + wc + n * 16 + (lane & 15);
        part[(size_t)bz * slice + (size_t)rr * ldc + cc] = acc[m][n][j];
      }
    }
  }
}

// ---- reduce GEMM1 fp16 partials: 8 slices + bias + bn1 + relu -> f16 ----
__global__ void reduce1h_k(const f16* __restrict__ parth, const float* __restrict__ bias,
                           const float* __restrict__ g, const float* __restrict__ b,
                           const float* __restrict__ m, const float* __restrict__ v,
                           f16* __restrict__ out) {
  const int i4 = (blockIdx.x * 256 + threadIdx.x) * 4;
  float s[4] = {0.f, 0.f, 0.f, 0.f};
#pragma unroll
  for (int z = 0; z < 8; z++) {
    const half4v p = *(const half4v*)(parth + (size_t)z * 1048576 + i4);
#pragma unroll
    for (int j = 0; j < 4; j++) s[j] += (float)p[j];
  }
  const int c0 = i4 & 1023;
  half4v o;
#pragma unroll
  for (int j = 0; j < 4; j++) {
    const int c = c0 + j;
    const float x = s[j] + bias[c];
    const float sc = g[c] / sqrtf(v[c] + 1e-3f);
    o[j] = (f16)fmaxf((x - m[c]) * sc + b[c], 0.f);
  }
  *(half4v*)(out + i4) = o;
}

// ---- split-K reduce + epilogue (fp32 partials): bias+BN+ReLU->f16 ----
template <int Z>
__global__ void reduce_ep_k(const float* __restrict__ part, int sliceE, int ldc,
                            const float* __restrict__ bias, const float* __restrict__ g,
                            const float* __restrict__ b, const float* __restrict__ m,
                            const float* __restrict__ v, f16* __restrict__ out) {
  const int i4 = (blockIdx.x * 256 + threadIdx.x) * 4;
  float4 s = *(const float4*)(part + i4);
#pragma unroll
  for (int z = 1; z < Z; z++) {
    const float4 p = *(const float4*)(part + (size_t)z * sliceE + i4);
    s.x += p.x; s.y += p.y; s.z += p.z; s.w += p.w;
  }
  const int c0 = i4 % ldc;
  float r[4] = {s.x, s.y, s.z, s.w};
  half4v o;
#pragma unroll
  for (int j = 0; j < 4; j++) {
    const int c = c0 + j;
    const float x = r[j] + bias[c];
    const float sc = g[c] / sqrtf(v[c] + 1e-3f);
    o[j] = (f16)fmaxf((x - m[c]) * sc + b[c], 0.f);
  }
  *(half4v*)(out + i4) = o;
}

// ---- fused: reduce GEMM3 partials (8 slices) + bias + softmax + scatter ----
__global__ __launch_bounds__(256) void reduce3_out_k(const float* __restrict__ part,
                                                     const float* __restrict__ bcat,
                                                     float* __restrict__ out) {
  const int r = blockIdx.x, t = threadIdx.x;
  __shared__ float red[256];
  const float* base = part + (size_t)r * 512;
  float v0 = 0.f, v1 = 0.f;
  {
    float s = bcat[t];
#pragma unroll
    for (int z = 0; z < 8; z++) s += base[(size_t)z * 524288 + t];
    v0 = s;
  }
  if (t < 149) {
    float s = bcat[256 + t];
#pragma unroll
    for (int z = 0; z < 8; z++) s += base[(size_t)z * 524288 + 256 + t];
    v1 = s;
  }
  red[t] = (t < 81) ? v0 : -INFINITY;
  __syncthreads();
  for (int s_ = 128; s_ > 0; s_ >>= 1) {
    if (t < s_) red[t] = fmaxf(red[t], red[t + s_]);
    __syncthreads();
  }
  const float mx = red[0];
  __syncthreads();
  const float e = (t < 81) ? expf(v0 - mx) : 0.f;
  red[t] = e;
  __syncthreads();
  for (int s_ = 128; s_ > 0; s_ >>= 1) {
    if (t < s_) red[t] += red[t + s_];
    __syncthreads();
  }
  const float inv = 1.f / red[0];
  if (t < 81) {
    out[(size_t)r * 81 + t] = v0;
    out[81000 + (size_t)r * 81 + t] = e * inv;
  }
  if (t >= 81) out[162000 + (size_t)r * 324 + (t - 81)] = v0;
  if (t < 149) out[162000 + (size_t)r * 324 + 175 + t] = v1;
}

extern "C" void kernel_launch(void* const* d_in, const int* in_sizes, int n_in,
                              void* d_out, int out_size, void* d_ws, size_t ws_size,
                              hipStream_t stream) {
  const float* p2 = (const float*)d_in[0];
  const float* p3 = (const float*)d_in[1];
  const float* p4 = (const float*)d_in[2];
  const float* p5 = (const float*)d_in[3];
  const float* rois = (const float*)d_in[4];
  const float* conv1_w = (const float*)d_in[5];
  const float* conv1_b = (const float*)d_in[6];
  const float* bn1_g = (const float*)d_in[7];
  const float* bn1_b = (const float*)d_in[8];
  const float* bn1_m = (const float*)d_in[9];
  const float* bn1_v = (const float*)d_in[10];
  const float* conv2_w = (const float*)d_in[11];
  const float* conv2_b = (const float*)d_in[12];
  const float* bn2_g = (const float*)d_in[13];
  const float* bn2_b = (const float*)d_in[14];
  const float* bn2_m = (const float*)d_in[15];
  const float* bn2_v = (const float*)d_in[16];
  const float* logits_w = (const float*)d_in[17];
  const float* logits_b = (const float*)d_in[18];
  const float* bbox_w = (const float*)d_in[19];
  const float* bbox_b = (const float*)d_in[20];

  char* ws = (char*)d_ws;
  f16* sh1 = (f16*)(ws + (size_t)0);
  f16* sh2 = (f16*)(ws + ((size_t)2 << 20));
  f16* w2t = (f16*)(ws + ((size_t)6 << 20));
  f16* wcat = (f16*)(ws + ((size_t)8 << 20));
  float* bcat = (float*)(ws + ((size_t)9 << 20));
  f16* fmapT = (f16*)(ws + (size_t)9961472);   // 9.5MB (dead after roi)
  f16* parth = (f16*)(ws + ((size_t)10 << 20));
  float* part = (float*)(ws + ((size_t)10 << 20));
  f16* pooled = (f16*)(ws + (size_t)44564480);
  f16* w1t = (f16*)(ws + (size_t)70254592);

  // 1) merged prep: gather(4 blk/roi) + fmap(64px) + w1t + small converts
  prep_all_k<<<6905, 256, 0, stream>>>(p2, p3, p4, p5, conv1_w, rois, conv2_w,
                                       logits_w, logits_b, bbox_w, bbox_b,
                                       fmapT, w1t, pooled, w2t, wcat, bcat);
  // 2) roi normal path: 2 blocks/roi, batched-load ILP
  roi_norm_k<<<2048, 256, 0, stream>>>(rois, fmapT, pooled);
  // 3) GEMM1: split-K=8, deep-pipeline engine, fp16 partials
  gemm1_d2<<<dim3(8, 4, 8), 512, 0, stream>>>(pooled, w1t, parth, 12544, 1568);
  reduce1h_k<<<1024, 256, 0, stream>>>(parth, conv1_b, bn1_g, bn1_b, bn1_m,
                                       bn1_v, sh1);
  // 4) GEMM2: split-K=4 (fp32 partials reuse part region)
  gemm_nt_p3<<<dim3(8, 8, 4), 256, 0, stream>>>(sh1, w2t, part, 1024, 256, 1024);
  reduce_ep_k<4><<<1024, 256, 0, stream>>>(part, 1048576, 1024, conv2_b, bn2_g,
                                           bn2_b, bn2_m, bn2_v, sh2);
  // 5) GEMM3: split-K=8
  gemm_nt_p3<<<dim3(4, 8, 8), 256, 0, stream>>>(sh2, wcat, part, 1024, 128, 512);
  // 6) fused reduce3 + softmax + output scatter
  reduce3_out_k<<<1000, 256, 0, stream>>>(part, bcat, (float*)d_out);
}

// Round 22
// 100.985 us; speedup vs baseline: 1.2354x; 1.0989x over previous
//
#include <hip/hip_runtime.h>
#include <hip/hip_fp16.h>
#include <math.h>

typedef _Float16 f16;
typedef _Float16 half8 __attribute__((ext_vector_type(8)));
typedef _Float16 half4v __attribute__((ext_vector_type(4)));
typedef _Float16 half2v __attribute__((ext_vector_type(2)));
typedef float f32x4 __attribute__((ext_vector_type(4)));

// ---------------- ws layout (bytes) ----------------
// sh1  @ 0MB   fp16 [1024][1024]
// sh2  @ 2MB   fp16 [1024][1024]
// w2t  @ 6MB   fp16 [1024][1024]
// wcat @ 8MB   fp16 [512][1024]
// bcat @ 9MB   fp32 [512]
// fmapT@ 9.5MB fp16 [21504][256]  (levels 3,4,5 at px 0,16384,20480) ends 20MB
// parth@ 10MB  f16 partials: gemm1 [8][1024][1024]=16MB; gemm2 [4][1024][1024]=8MB;
//              gemm3 [8][1024][512]=8MB (sequential reuse), ends < 42MB
// pooled @ 44,564,480  fp16 [1024][49*256]
// w1t    @ 70,254,592  fp16 [1024][49*256]   (total 95,944,704 B)

__device__ __forceinline__ void gload16(const void* g, void* lds) {
  __builtin_amdgcn_global_load_lds(
      (const __attribute__((address_space(1))) unsigned int*)g,
      (__attribute__((address_space(3))) unsigned int*)lds, 16, 0, 0);
}

// ======== prep bodies (r21-proven, unchanged) ========
__device__ __forceinline__ void fmap_body64(int b, f16* tile,
                                            const float* __restrict__ p3,
                                            const float* __restrict__ p4,
                                            const float* __restrict__ p5,
                                            f16* __restrict__ dst0) {
  const float* src;
  int Ppix, p0;
  size_t dstoff;
  if (b < 256)      { src = p3; Ppix = 16384; dstoff = 0;     p0 = b * 64; }
  else if (b < 320) { src = p4; Ppix = 4096;  dstoff = 16384; p0 = (b - 256) * 64; }
  else              { src = p5; Ppix = 1024;  dstoff = 20480; p0 = (b - 320) * 64; }
  const int t = threadIdx.x;
  const int px4 = (t & 15) * 4;   // 0..60
  const int cp = (t >> 4) * 2;    // 0..30
#pragma unroll
  for (int i = 0; i < 8; i++) {
    const int c = i * 32 + cp;
    const float4 va = *(const float4*)&src[(size_t)c * Ppix + p0 + px4];
    const float4 vb = *(const float4*)&src[(size_t)(c + 1) * Ppix + p0 + px4];
    const float a_[4] = {va.x, va.y, va.z, va.w};
    const float b_[4] = {vb.x, vb.y, vb.z, vb.w};
#pragma unroll
    for (int j = 0; j < 4; j++) {
      const int px = px4 + j;
      const int cs = c ^ (((px >> 2) & 31) << 3);  // flips bits>=3, parity kept
      half2v h = {(f16)a_[j], (f16)b_[j]};
      *(half2v*)&tile[px * 256 + cs] = h;
    }
  }
  __syncthreads();
  f16* d = dst0 + (dstoff + (size_t)p0) * 256;
  const int c8 = (t & 31) * 8;
  const int pxw = t >> 5;  // 0..7
#pragma unroll
  for (int i = 0; i < 8; i++) {
    const int px = i * 8 + pxw;
    const int c8s = c8 ^ (((px >> 2) & 31) << 3);
    const half8 o = *(const half8*)&tile[px * 256 + c8s];
    *(half8*)&d[px * 256 + c8] = o;
  }
}

// w1 repack v3 (r16-proven): phase-1 via global_load_lds.
// buf layout: raw fp32 [6272] at buf[0] (25,088B); tile f16 [49*260] at buf+12544.
__device__ __forceinline__ void w1t_body(int k, f16* buf,
                                         const float* __restrict__ w1,
                                         f16* __restrict__ w1t) {
  const int t = threadIdx.x;
  float* raw = (float*)buf;
  f16* tile = buf + 12544;
  const float* src = w1 + (size_t)k * 12544;
  f16* dst = w1t + (size_t)k * 12544;
#pragma unroll
  for (int h = 0; h < 2; h++) {
    const float* sh_ = src + h * 6272;   // c in [128h, 128h+128): 6272 floats
#pragma unroll
    for (int j = 0; j < 6; j++)
      gload16(sh_ + (size_t)(j * 256 + t) * 4, raw + (size_t)(j * 256 + t) * 4);
    float4 tail;
    if (t < 32) tail = *(const float4*)&sh_[(1536 + t) * 4];
    asm volatile("s_waitcnt vmcnt(0)" ::: "memory");
    __builtin_amdgcn_sched_barrier(0);
    if (t < 32) *(float4*)&raw[(1536 + t) * 4] = tail;
    __syncthreads();
#pragma unroll
    for (int i = 0; i < 25; i++) {
      const int v = i * 256 + t;
      if (v < 6272) {
        const int c = v / 49, pq = v - c * 49;
        tile[pq * 260 + (h * 128 + c)] = (f16)raw[v];
      }
    }
    __syncthreads();
  }
#pragma unroll
  for (int i = 0; i < 7; i++) {
    const int h8 = i * 256 + t;
    if (h8 < 1568) {
      const int pq = h8 >> 5, c8 = (h8 & 31) * 8;
      const half4v lo = *(const half4v*)&tile[pq * 260 + c8];
      const half4v hi = *(const half4v*)&tile[pq * 260 + c8 + 4];
      half8 o;
      o[0] = lo[0]; o[1] = lo[1]; o[2] = lo[2]; o[3] = lo[3];
      o[4] = hi[0]; o[5] = hi[1]; o[6] = hi[2]; o[7] = hi[3];
      *(half8*)&dst[pq * 256 + c8] = o;
    }
  }
}

// grid = 6905: [0,4000) gather (4 blocks/roi, 64ch each); [4000,5368) {1 fmap :
// 3 w1t} groups; [5368,6905) small converts.   (r21-proven)
__global__ __launch_bounds__(256) void prep_all_k(
    const float* __restrict__ p2, const float* __restrict__ p3,
    const float* __restrict__ p4, const float* __restrict__ p5,
    const float* __restrict__ conv1_w, const float* __restrict__ rois,
    const float* __restrict__ conv2_w, const float* __restrict__ lw,
    const float* __restrict__ lb, const float* __restrict__ bw,
    const float* __restrict__ bb, f16* __restrict__ fmapT,
    f16* __restrict__ w1t, f16* __restrict__ pooled, f16* __restrict__ w2t,
    f16* __restrict__ wcat, float* __restrict__ bcat) {
  __shared__ __align__(16) f16 buf[25600];  // 50 KB union
  const int bid = blockIdx.x;
  const int t = threadIdx.x;
  if (bid < 4000) {
    // ---- level-2 gather v4: 4 blocks/roi, 64 channels each ----
    const int r = bid >> 2, q = bid & 3;
    const float x1 = rois[r * 4 + 0], y1 = rois[r * 4 + 1];
    const float x2 = rois[r * 4 + 2], y2 = rois[r * 4 + 3];
    const float s = sqrtf(fmaxf((y2 - y1) * (x2 - x1), 0.f));
    const float lf = logf(s / 224.0f) / 0.69314718055994531f;
    int lv = (int)rintf(lf) + 4;
    lv = lv < 2 ? 2 : (lv > 5 ? 5 : lv);
    if (lv != 2) return;
    const int wid = t >> 6, lane = t & 63;
    const float Hm1 = 255.f;
    int o00 = 0, o01 = 0, o10 = 0, o11 = 0;
    float wxl = 0.f, wyl = 0.f;
    bool vv = false;
    if (lane < 49) {
      const int py = lane / 7, px = lane % 7;
      const float y1n = y1 * (1.0f / 1024.0f), y2n = y2 * (1.0f / 1024.0f);
      const float x1n = x1 * (1.0f / 1024.0f), x2n = x2 * (1.0f / 1024.0f);
      const float cyc = y1n * Hm1 + ((float)py / 6.0f) * ((y2n - y1n) * Hm1);
      const float cxc = x1n * Hm1 + ((float)px / 6.0f) * ((x2n - x1n) * Hm1);
      const bool vy = (cyc >= 0.f) && (cyc <= Hm1);
      const bool vx = (cxc >= 0.f) && (cxc <= Hm1);
      float cy = fminf(fmaxf(cyc, 0.f), Hm1);
      float cx = fminf(fmaxf(cxc, 0.f), Hm1);
      const float fy = floorf(cy), fx = floorf(cx);
      const int ylo = (int)fy, xlo = (int)fx;
      const int yhi = (int)fminf(fy + 1.f, Hm1);
      const int xhi = (int)fminf(fx + 1.f, Hm1);
      wyl = cy - fy;
      wxl = cx - fx;
      vv = vy && vx;
      o00 = ylo * 256 + xlo;
      o01 = ylo * 256 + xhi;
      o10 = yhi * 256 + xlo;
      o11 = yhi * 256 + xhi;
    }
#pragma unroll 4
    for (int ci = 0; ci < 16; ci++) {
      const int chL = ci * 4 + wid;  // local channel 0..63
      const float* pc = p2 + (size_t)(q * 64 + chL) * 65536;
      if (lane < 49) {
        const float v00 = pc[o00], v01 = pc[o01];
        const float v10 = pc[o10], v11 = pc[o11];
        const float top = v00 * (1.f - wxl) + v01 * wxl;
        const float bot = v10 * (1.f - wxl) + v11 * wxl;
        float val = top * (1.f - wyl) + bot * wyl;
        if (!vv) val = 0.f;
        buf[lane * 257 + chL] = (f16)val;
      }
    }
    __syncthreads();
    f16* outp = pooled + (size_t)r * 12544 + q * 64;
#pragma unroll
    for (int i = 0; i < 13; i++) {
      const int idx = i * 256 + t;
      if (idx < 3136) {
        const int pos = idx >> 6, c = idx & 63;
        outp[(size_t)pos * 256 + c] = buf[pos * 257 + c];
      }
    }
    return;
  }
  if (bid < 5368) {
    const int b2 = bid - 4000;
    const int g = b2 >> 2, rr = b2 & 3;
    if (rr == 0) {
      if (g < 336) fmap_body64(g, buf, p3, p4, p5, fmapT);
    } else {
      const int wb = g * 3 + (rr - 1);
      if (wb < 1024) w1t_body(wb, buf, conv1_w, w1t);
    }
    return;
  }
  // ---- small converts (r3-proven body) ----
  const int i = (bid - 5368) * 256 + t;
  if (i < 262144) {
    const float4 v = ((const float4*)conv2_w)[i];
    half4v o = {(f16)v.x, (f16)v.y, (f16)v.z, (f16)v.w};
    ((half4v*)w2t)[i] = o;
  } else if (i < 262144 + 131072) {
    const int idx4 = i - 262144;
    const int elem = idx4 * 4;
    const int row = elem >> 10, col = elem & 1023;
    half4v o;
#pragma unroll
    for (int j = 0; j < 4; j++) {
      float v = 0.f;
      if (row < 81) v = lw[row * 1024 + col + j];
      else if (row < 405) v = bw[(row - 81) * 1024 + col + j];
      o[j] = (f16)v;
    }
    ((half4v*)wcat)[idx4] = o;
  } else if (i < 262144 + 131072 + 128) {
    const int j = (i - 393216) * 4;
    float r_[4];
#pragma unroll
    for (int q = 0; q < 4; q++) {
      const int c = j + q;
      float bv = 0.f;
      if (c < 81) bv = lb[c];
      else if (c < 405) bv = bb[c - 81];
      r_[q] = bv;
    }
    float4 o;
    o.x = r_[0]; o.y = r_[1]; o.z = r_[2]; o.w = r_[3];
    *(float4*)&bcat[j] = o;
  }
}

// ---- roi normal path v5 (r13-proven): 2 blocks/roi, batched-16-load ILP ----
__global__ __launch_bounds__(256) void roi_norm_k(const float* __restrict__ rois,
                                                  const f16* __restrict__ fmapT,
                                                  f16* __restrict__ pooled) {
  const int bid = blockIdx.x;
  const int r = bid >> 1, h = bid & 1;
  const int t = threadIdx.x;
  const int npos = h ? 24 : 25;
  const int pbase = h ? 25 : 0;
  if (r >= 1000) {
    f16* outp = pooled + (size_t)r * 12544 + t;
    for (int i = 0; i < npos; i++) outp[(pbase + i) * 256] = (f16)0.f;
    return;
  }
  __shared__ int s_lo[14], s_hi[14], s_val[14];
  __shared__ float s_w[14];
  __shared__ int q00[25], q01[25], q10[25], q11[25], qv[25];
  __shared__ float qwx[25], qwy[25];
  const float x1 = rois[r * 4 + 0], y1 = rois[r * 4 + 1];
  const float x2 = rois[r * 4 + 2], y2 = rois[r * 4 + 3];
  const float s = sqrtf(fmaxf((y2 - y1) * (x2 - x1), 0.f));
  const float lf = logf(s / 224.0f) / 0.69314718055994531f;
  int lv = (int)rintf(lf) + 4;
  lv = lv < 2 ? 2 : (lv > 5 ? 5 : lv);
  const int li = lv - 2;
  if (li == 0) return;  // level-2 handled in prep_all_k
  const int H = 256 >> li;
  const int off = (li == 1) ? 0 : (li == 2) ? 16384 : 20480;
  const float Hm1 = (float)(H - 1);
  if (t < 14) {
    const bool isx = t >= 7;
    const int i = isx ? t - 7 : t;
    const float b1 = (isx ? x1 : y1) * (1.0f / 1024.0f);
    const float b2 = (isx ? x2 : y2) * (1.0f / 1024.0f);
    const float g = (float)i / 6.0f;
    const float coord = b1 * Hm1 + g * ((b2 - b1) * Hm1);
    const int valid = (coord >= 0.f) && (coord <= Hm1);
    float c = fminf(fmaxf(coord, 0.f), Hm1);
    float lo = floorf(c);
    s_lo[t] = (int)lo;
    s_hi[t] = (int)fminf(lo + 1.f, Hm1);
    s_w[t] = c - lo;
    s_val[t] = valid;
  }
  __syncthreads();
  if (t < npos) {
    const int pos = pbase + t;
    const int py = pos / 7, px = pos - py * 7;
    q00[t] = (s_lo[py] * H + s_lo[7 + px]) * 256;
    q01[t] = (s_lo[py] * H + s_hi[7 + px]) * 256;
    q10[t] = (s_hi[py] * H + s_lo[7 + px]) * 256;
    q11[t] = (s_hi[py] * H + s_hi[7 + px]) * 256;
    qwx[t] = s_w[7 + px];
    qwy[t] = s_w[py];
    qv[t] = s_val[py] && s_val[7 + px];
  }
  __syncthreads();
  const int c8 = (t & 31) * 8;
  const int g = t >> 5;
  const f16* base = fmapT + (size_t)off * 256 + c8;
  f16* outp = pooled + (size_t)r * 12544 + c8;
  int o00[4], o01[4], o10[4], o11[4], pw[4], ok[4], act[4];
  float wx[4], wy[4];
#pragma unroll
  for (int i = 0; i < 4; i++) {
    const int j = g + i * 8;
    act[i] = (j < npos);
    const int jj = act[i] ? j : 0;
    o00[i] = q00[jj]; o01[i] = q01[jj]; o10[i] = q10[jj]; o11[i] = q11[jj];
    wx[i] = qwx[jj]; wy[i] = qwy[jj]; ok[i] = qv[jj];
    pw[i] = (pbase + jj) * 256;
  }
  half8 v00[4], v01[4], v10[4], v11[4];
#pragma unroll
  for (int i = 0; i < 4; i++) {
    v00[i] = *(const half8*)&base[o00[i]];
    v01[i] = *(const half8*)&base[o01[i]];
    v10[i] = *(const half8*)&base[o10[i]];
    v11[i] = *(const half8*)&base[o11[i]];
  }
  __builtin_amdgcn_sched_barrier(0);
#pragma unroll
  for (int i = 0; i < 4; i++) {
    if (act[i]) {
      half8 o;
#pragma unroll
      for (int q = 0; q < 8; q++) {
        const float top = (float)v00[i][q] * (1.f - wx[i]) + (float)v01[i][q] * wx[i];
        const float bot = (float)v10[i][q] * (1.f - wx[i]) + (float)v11[i][q] * wx[i];
        float vvq = top * (1.f - wy[i]) + bot * wy[i];
        if (!ok[i]) vvq = 0.f;
        o[q] = (f16)vvq;
      }
      *(half8*)&outp[pw[i]] = o;
    }
  }
}

// ---- GEMM1 engine v2 (r5-proven): 8-wave 256x128, BK=32, 4-slot ring ----
// fp16 partials: parth[z][1024][1024].
__global__ __launch_bounds__(512) void gemm1_d2(
    const f16* __restrict__ A, const f16* __restrict__ B, f16* __restrict__ parth,
    int K, int kPerSplit) {
  __shared__ __align__(16) f16 As[4][256 * 32];   // 64 KB
  __shared__ __align__(16) f16 Bs[4][128 * 32];   // 32 KB
  const int t = threadIdx.x;

  int lid = blockIdx.x + 8 * (blockIdx.y + 4 * blockIdx.z);
  const int chunk = (8 * 4 * (int)gridDim.z) >> 3;
  lid = (lid & 7) * chunk + (lid >> 3);
  const int bx = lid & 7;
  const int by = (lid >> 3) & 3;
  const int bz = lid >> 5;

  const int m0 = by * 256, n0 = bx * 128;
  const int wid = t >> 6, lane = t & 63;
  const int wr = (wid & 3) * 64;   // 4 M-waves
  const int wc = (wid >> 2) * 64;  // 2 N-waves
  const int lrow = lane & 15;
  const int lsl = lane >> 4;
  const int srow = t >> 2;                              // 0..127 staging row
  const int scol = (((t & 3) ^ ((t >> 3) & 3)) << 3);   // pre-swizzled source slot
  const int kz0 = bz * kPerSplit;
  const int nIter = kPerSplit >> 5;

  f32x4 acc[4][4] = {};
  const f16* Ab = A + (size_t)(m0 + srow) * K + kz0 + scol;
  const f16* Bb = B + (size_t)(n0 + srow) * K + kz0 + scol;
  f16* asb = &As[0][0] + wid * 512;  // wave-uniform base within slot
  f16* bsb = &Bs[0][0] + wid * 512;

#define STG(kt) do {                                                           \
    const int sl_ = (kt) & 3; const size_t ko_ = (size_t)(kt) * 32;            \
    gload16(Ab + ko_, asb + sl_ * 8192);                                       \
    gload16(Ab + (size_t)128 * K + ko_, asb + sl_ * 8192 + 4096);              \
    gload16(Bb + ko_, bsb + sl_ * 4096);                                       \
    __builtin_amdgcn_sched_barrier(0);                                         \
  } while (0)

  STG(0);
  STG(1);
  asm volatile("s_waitcnt vmcnt(3)" ::: "memory");  // tile 0 resident
  __builtin_amdgcn_sched_barrier(0);
  __builtin_amdgcn_s_barrier();

  for (int kt = 0; kt < nIter; ++kt) {
    const int sl = kt & 3;
    const f16* as = &As[sl][0];
    const f16* bs = &Bs[sl][0];
    half8 aF[4], bF[4];
#pragma unroll
    for (int m = 0; m < 4; m++) {
      const int r_ = wr + m * 16 + lrow;
      aF[m] = *(const half8*)&as[r_ * 32 + ((lsl ^ ((r_ >> 1) & 3)) << 3)];
    }
#pragma unroll
    for (int n = 0; n < 4; n++) {
      const int r_ = wc + n * 16 + lrow;
      bF[n] = *(const half8*)&bs[r_ * 32 + ((lsl ^ ((r_ >> 1) & 3)) << 3)];
    }
    if (kt + 2 < nIter) STG(kt + 2);
    __builtin_amdgcn_s_setprio(1);
#pragma unroll
    for (int m = 0; m < 4; m++)
#pragma unroll
      for (int n = 0; n < 4; n++)
        acc[m][n] = __builtin_amdgcn_mfma_f32_16x16x32_f16(aF[m], bF[n], acc[m][n], 0, 0, 0);
    __builtin_amdgcn_s_setprio(0);
    if (kt + 2 < nIter) { asm volatile("s_waitcnt vmcnt(3)" ::: "memory"); }
    else                { asm volatile("s_waitcnt vmcnt(0)" ::: "memory"); }
    __builtin_amdgcn_sched_barrier(0);
    __builtin_amdgcn_s_barrier();
  }
#undef STG

  f16* outp = parth + (size_t)bz * (1024 * 1024);
#pragma unroll
  for (int m = 0; m < 4; m++) {
    const int rr = m0 + wr + m * 16 + lsl * 4;
#pragma unroll
    for (int n = 0; n < 4; n++) {
      const int cc = n0 + wc + n * 16 + lrow;
#pragma unroll
      for (int j = 0; j < 4; j++)
        outp[(size_t)(rr + j) * 1024 + cc] = (f16)acc[m][n][j];
    }
  }
}

// ---- GEMM2/3 engine (r3-proven), templated output type (f16 partials) ----
template <typename OutT>
__global__ __launch_bounds__(256) void gemm_nt_p3(
    const f16* __restrict__ A, const f16* __restrict__ B, OutT* __restrict__ part,
    int K, int kPerSplit, int ldc) {
  __shared__ __align__(16) f16 As[3][128 * 32];
  __shared__ __align__(16) f16 Bs[3][128 * 32];
  const int t = threadIdx.x;

  const int gx = gridDim.x, gy = gridDim.y;
  int lid = blockIdx.x + gx * (blockIdx.y + gy * blockIdx.z);
  const int chunk = (gx * gy * (int)gridDim.z) >> 3;
  lid = (lid & 7) * chunk + (lid >> 3);
  const int bx = lid % gx;
  const int tmp = lid / gx;
  const int by = tmp % gy;
  const int bz = tmp / gy;

  const int m0 = by * 128;
  const int n0 = bx * 128;
  const int wid = t >> 6;
  const int lane = t & 63;
  const int wr = (wid >> 1) * 64;
  const int wc = (wid & 1) * 64;
  const int lrow = lane & 15;
  const int lsl = lane >> 4;
  const int rowA = t >> 2;
  const int c8 = (((t & 3) ^ ((rowA >> 1) & 3)) << 3);
  const int kz0 = bz * kPerSplit;
  const int nIter = kPerSplit >> 5;

  f32x4 acc[4][4] = {};
  const f16* Ab = A + (size_t)m0 * K + kz0 + c8;
  const f16* Bb = B + (size_t)n0 * K + kz0 + c8;

#define STAGE(buf, it)                                                        \
  do {                                                                        \
    const int ko = (it) * 32;                                                 \
    gload16(Ab + (size_t)rowA * K + ko, &As[buf][wid * 512]);                 \
    gload16(Ab + (size_t)(rowA + 64) * K + ko, &As[buf][2048 + wid * 512]);   \
    gload16(Bb + (size_t)rowA * K + ko, &Bs[buf][wid * 512]);                 \
    gload16(Bb + (size_t)(rowA + 64) * K + ko, &Bs[buf][2048 + wid * 512]);   \
  } while (0)

#define COMPUTE(buf)                                                          \
  do {                                                                        \
    half8 aF[4], bF[4];                                                       \
    _Pragma("unroll") for (int m = 0; m < 4; m++) {                           \
      const int rr_ = wr + m * 16 + lrow;                                     \
      aF[m] = *(const half8*)&As[buf][rr_ * 32 + ((lsl ^ ((rr_ >> 1) & 3)) << 3)]; \
    }                                                                         \
    _Pragma("unroll") for (int n = 0; n < 4; n++) {                           \
      const int rr_ = wc + n * 16 + lrow;                                     \
      bF[n] = *(const half8*)&Bs[buf][rr_ * 32 + ((lsl ^ ((rr_ >> 1) & 3)) << 3)]; \
    }                                                                         \
    __builtin_amdgcn_s_setprio(1);                                            \
    _Pragma("unroll") for (int m = 0; m < 4; m++)                             \
      _Pragma("unroll") for (int n = 0; n < 4; n++)                           \
        acc[m][n] = __builtin_amdgcn_mfma_f32_16x16x32_f16(aF[m], bF[n], acc[m][n], 0, 0, 0); \
    __builtin_amdgcn_s_setprio(0);                                            \
  } while (0)

  STAGE(0, 0);
  STAGE(1, 1);
  int bc = 0;
  for (int it = 0; it < nIter - 2; ++it) {
    const int bs_ = (bc == 0) ? 2 : bc - 1;
    STAGE(bs_, it + 2);
    asm volatile("s_waitcnt vmcnt(8)" ::: "memory");
    __builtin_amdgcn_sched_barrier(0);
    __builtin_amdgcn_s_barrier();
    COMPUTE(bc);
    __builtin_amdgcn_s_barrier();
    bc = (bc == 2) ? 0 : bc + 1;
  }
  asm volatile("s_waitcnt vmcnt(4)" ::: "memory");
  __builtin_amdgcn_sched_barrier(0);
  __builtin_amdgcn_s_barrier();
  COMPUTE(bc);
  __builtin_amdgcn_s_barrier();
  bc = (bc == 2) ? 0 : bc + 1;
  asm volatile("s_waitcnt vmcnt(0)" ::: "memory");
  __builtin_amdgcn_sched_barrier(0);
  __builtin_amdgcn_s_barrier();
  COMPUTE(bc);
#undef STAGE
#undef COMPUTE

  const size_t slice = (size_t)gy * 128 * ldc;
#pragma unroll
  for (int m = 0; m < 4; m++) {
#pragma unroll
    for (int n = 0; n < 4; n++) {
#pragma unroll
      for (int j = 0; j < 4; j++) {
        const int rr = m0 + wr + m * 16 + ((lane >> 4) << 2) + j;
        const int cc = n0 + wc + n * 16 + (lane & 15);
        part[(size_t)bz * slice + (size_t)rr * ldc + cc] = (OutT)acc[m][n][j];
      }
    }
  }
}

// ---- reduce f16 partials (Z slices, slice stride in elements) + BN + ReLU ----
template <int Z, int SLICE>
__global__ void reduceh_k(const f16* __restrict__ parth, const float* __restrict__ bias,
                          const float* __restrict__ g, const float* __restrict__ b,
                          const float* __restrict__ m, const float* __restrict__ v,
                          f16* __restrict__ out) {
  const int i4 = (blockIdx.x * 256 + threadIdx.x) * 4;
  float s[4] = {0.f, 0.f, 0.f, 0.f};
#pragma unroll
  for (int z = 0; z < Z; z++) {
    const half4v p = *(const half4v*)(parth + (size_t)z * SLICE + i4);
#pragma unroll
    for (int j = 0; j < 4; j++) s[j] += (float)p[j];
  }
  const int c0 = i4 & 1023;
  half4v o;
#pragma unroll
  for (int j = 0; j < 4; j++) {
    const int c = c0 + j;
    const float x = s[j] + bias[c];
    const float sc = g[c] / sqrtf(v[c] + 1e-3f);
    o[j] = (f16)fmaxf((x - m[c]) * sc + b[c], 0.f);
  }
  *(half4v*)(out + i4) = o;
}

// ---- fused: reduce GEMM3 f16 partials (8 slices) + bias + softmax + scatter ----
__global__ __launch_bounds__(256) void reduce3_out_k(const f16* __restrict__ parth,
                                                     const float* __restrict__ bcat,
                                                     float* __restrict__ out) {
  const int r = blockIdx.x, t = threadIdx.x;
  __shared__ float red[256];
  const f16* base = parth + (size_t)r * 512;
  float v0 = 0.f, v1 = 0.f;
  {
    float s = bcat[t];
#pragma unroll
    for (int z = 0; z < 8; z++) s += (float)base[(size_t)z * 524288 + t];
    v0 = s;
  }
  if (t < 149) {
    float s = bcat[256 + t];
#pragma unroll
    for (int z = 0; z < 8; z++) s += (float)base[(size_t)z * 524288 + 256 + t];
    v1 = s;
  }
  red[t] = (t < 81) ? v0 : -INFINITY;
  __syncthreads();
  for (int s_ = 128; s_ > 0; s_ >>= 1) {
    if (t < s_) red[t] = fmaxf(red[t], red[t + s_]);
    __syncthreads();
  }
  const float mx = red[0];
  __syncthreads();
  const float e = (t < 81) ? expf(v0 - mx) : 0.f;
  red[t] = e;
  __syncthreads();
  for (int s_ = 128; s_ > 0; s_ >>= 1) {
    if (t < s_) red[t] += red[t + s_];
    __syncthreads();
  }
  const float inv = 1.f / red[0];
  if (t < 81) {
    out[(size_t)r * 81 + t] = v0;
    out[81000 + (size_t)r * 81 + t] = e * inv;
  }
  if (t >= 81) out[162000 + (size_t)r * 324 + (t - 81)] = v0;
  if (t < 149) out[162000 + (size_t)r * 324 + 175 + t] = v1;
}

extern "C" void kernel_launch(void* const* d_in, const int* in_sizes, int n_in,
                              void* d_out, int out_size, void* d_ws, size_t ws_size,
                              hipStream_t stream) {
  const float* p2 = (const float*)d_in[0];
  const float* p3 = (const float*)d_in[1];
  const float* p4 = (const float*)d_in[2];
  const float* p5 = (const float*)d_in[3];
  const float* rois = (const float*)d_in[4];
  const float* conv1_w = (const float*)d_in[5];
  const float* conv1_b = (const float*)d_in[6];
  const float* bn1_g = (const float*)d_in[7];
  const float* bn1_b = (const float*)d_in[8];
  const float* bn1_m = (const float*)d_in[9];
  const float* bn1_v = (const float*)d_in[10];
  const float* conv2_w = (const float*)d_in[11];
  const float* conv2_b = (const float*)d_in[12];
  const float* bn2_g = (const float*)d_in[13];
  const float* bn2_b = (const float*)d_in[14];
  const float* bn2_m = (const float*)d_in[15];
  const float* bn2_v = (const float*)d_in[16];
  const float* logits_w = (const float*)d_in[17];
  const float* logits_b = (const float*)d_in[18];
  const float* bbox_w = (const float*)d_in[19];
  const float* bbox_b = (const float*)d_in[20];

  char* ws = (char*)d_ws;
  f16* sh1 = (f16*)(ws + (size_t)0);
  f16* sh2 = (f16*)(ws + ((size_t)2 << 20));
  f16* w2t = (f16*)(ws + ((size_t)6 << 20));
  f16* wcat = (f16*)(ws + ((size_t)8 << 20));
  float* bcat = (float*)(ws + ((size_t)9 << 20));
  f16* fmapT = (f16*)(ws + (size_t)9961472);   // 9.5MB (dead after roi)
  f16* parth = (f16*)(ws + ((size_t)10 << 20));
  f16* pooled = (f16*)(ws + (size_t)44564480);
  f16* w1t = (f16*)(ws + (size_t)70254592);

  // 1) merged prep: gather(4 blk/roi) + fmap(64px) + w1t + small converts
  prep_all_k<<<6905, 256, 0, stream>>>(p2, p3, p4, p5, conv1_w, rois, conv2_w,
                                       logits_w, logits_b, bbox_w, bbox_b,
                                       fmapT, w1t, pooled, w2t, wcat, bcat);
  // 2) roi normal path: 2 blocks/roi, batched-load ILP
  roi_norm_k<<<2048, 256, 0, stream>>>(rois, fmapT, pooled);
  // 3) GEMM1: split-K=8, deep-pipeline engine, fp16 partials
  gemm1_d2<<<dim3(8, 4, 8), 512, 0, stream>>>(pooled, w1t, parth, 12544, 1568);
  reduceh_k<8, 1048576><<<1024, 256, 0, stream>>>(parth, conv1_b, bn1_g, bn1_b,
                                                  bn1_m, bn1_v, sh1);
  // 4) GEMM2: split-K=4, f16 partials
  gemm_nt_p3<f16><<<dim3(8, 8, 4), 256, 0, stream>>>(sh1, w2t, parth, 1024, 256, 1024);
  reduceh_k<4, 1048576><<<1024, 256, 0, stream>>>(parth, conv2_b, bn2_g, bn2_b,
                                                  bn2_m, bn2_v, sh2);
  // 5) GEMM3: split-K=8, f16 partials
  gemm_nt_p3<f16><<<dim3(4, 8, 8), 256, 0, stream>>>(sh2, wcat, parth, 1024, 128, 512);
  // 6) fused reduce3 + softmax + output scatter (reads f16 partials)
  reduce3_out_k<<<1000, 256, 0, stream>>>(parth, bcat, (float*)d_out);
}